// Round 1
// baseline (369.663 us; speedup 1.0000x reference)
//
#include <hip/hip_runtime.h>
#include <math.h>

// Problem constants: T=512, B=256, D=256, H=4 (N_Q). Only gate wires 0,1 depend
// on the input; wires 2,3 are deterministic (cos(phi) only) -> closed form.
#define TT 512
#define BB 256
#define DD 256
#define ROWS (TT * BB)          // 131072
#define INV2PI 0.15915494309189535f
#define L2E 1.4426950408889634f

__device__ __forceinline__ float cosr(float rev) {
    // v_cos_f32: cos(2*pi*rev). |rev| <~ 2 here, well within accurate domain.
    return __builtin_amdgcn_cosf(rev);
}
__device__ __forceinline__ float fast_sig(float x) {
    float e = __builtin_amdgcn_exp2f(-L2E * x);
    return __builtin_amdgcn_rcpf(1.0f + e);
}
__device__ __forceinline__ float fast_tanh(float x) {
    float e = __builtin_amdgcn_exp2f(2.0f * L2E * x);
    return 1.0f - 2.0f * __builtin_amdgcn_rcpf(e + 1.0f);
}

// Multi-value butterfly: sum p[0..7] across 64 lanes with 10 shuffles.
// On return, every lane holds the full sum of value index v = 4*(l&1)+2*((l>>1)&1)+((l>>2)&1).
__device__ __forceinline__ float reduce8(float p[8], int lane) {
    const bool b0 = lane & 1;
#pragma unroll
    for (int k = 0; k < 4; ++k) {
        float send = b0 ? p[k] : p[k + 4];
        float q = __shfl_xor(send, 1, 64);
        p[k] = (b0 ? p[k + 4] : p[k]) + q;
    }
    const bool b1 = lane & 2;
#pragma unroll
    for (int k = 0; k < 2; ++k) {
        float send = b1 ? p[k] : p[k + 2];
        float q = __shfl_xor(send, 2, 64);
        p[k] = (b1 ? p[k + 2] : p[k]) + q;
    }
    const bool b2 = lane & 4;
    {
        float send = b2 ? p[0] : p[1];
        float q = __shfl_xor(send, 4, 64);
        p[0] = (b2 ? p[1] : p[0]) + q;
    }
    p[0] += __shfl_xor(p[0], 8, 64);
    p[0] += __shfl_xor(p[0], 16, 64);
    p[0] += __shfl_xor(p[0], 32, 64);
    return p[0];
}

// Kernel A: Z[t, b, idx] = (x[t,b,:] . W_g[wire, 0:256]) * INV2PI, idx = g*2+wire.
// One wave per row: 64 lanes x float4 = the whole 256-float row, perfectly coalesced.
__global__ __launch_bounds__(256) void qlstm_gemm(
    const float* __restrict__ x,
    const float* __restrict__ Wf, const float* __restrict__ Wi,
    const float* __restrict__ Wu, const float* __restrict__ Wo,
    float* __restrict__ Z) {
    const int lane = threadIdx.x & 63;
    const int wid = (blockIdx.x * blockDim.x + threadIdx.x) >> 6;  // 0..8191
    const float* Ws[4] = {Wf, Wi, Wu, Wo};

    // Per-lane weight fragments: W_g[wire, 4*lane .. 4*lane+3]
    float4 wv[8];
#pragma unroll
    for (int g = 0; g < 4; ++g) {
#pragma unroll
        for (int wire = 0; wire < 2; ++wire) {
            wv[g * 2 + wire] = *(const float4*)(Ws[g] + wire * 260 + 4 * lane);
        }
    }
    const int v = ((lane & 1) << 2) | (lane & 2) | ((lane >> 2) & 1);

    // Two rows per iteration (2 loads in flight per wave for latency hiding).
    for (int r0 = wid; r0 < ROWS; r0 += 16384) {
        const int r1 = r0 + 8192;
        float4 xa = *(const float4*)(x + (size_t)r0 * DD + 4 * lane);
        float4 xb = *(const float4*)(x + (size_t)r1 * DD + 4 * lane);
        float pa[8], pb[8];
#pragma unroll
        for (int j = 0; j < 8; ++j) {
            pa[j] = xa.x * wv[j].x + xa.y * wv[j].y + xa.z * wv[j].z + xa.w * wv[j].w;
            pb[j] = xb.x * wv[j].x + xb.y * wv[j].y + xb.z * wv[j].z + xb.w * wv[j].w;
        }
        float sa = reduce8(pa, lane);
        float sb = reduce8(pb, lane);
        if (lane < 8) {
            Z[(size_t)r0 * 8 + v] = sa * INV2PI;
            Z[(size_t)r1 * 8 + v] = sb * INV2PI;
        }
    }
}

// Kernel B: per-batch-element 512-step scan. idx order: f0,f1,i0,i1,u0,u1,o0,o1.
__global__ __launch_bounds__(64) void qlstm_scan(
    const float* __restrict__ Z,
    const float* __restrict__ Wf, const float* __restrict__ bf, const float* __restrict__ pf,
    const float* __restrict__ Wi, const float* __restrict__ bi, const float* __restrict__ pi,
    const float* __restrict__ Wu, const float* __restrict__ bu, const float* __restrict__ pu,
    const float* __restrict__ Wo, const float* __restrict__ bo, const float* __restrict__ po,
    float* __restrict__ out) {
    __shared__ __align__(16) float hc[TT][8];    // per-step constant part of angle (revolutions)
    __shared__ __align__(16) float hout[TT][2];  // h_{t+1}[2], h_{t+1}[3]
    const int tid = threadIdx.x;  // 0..63, single wave per block
    const int b = blockIdx.x * 64 + tid;

    const float* Ws[4] = {Wf, Wi, Wu, Wo};
    const float* Bs[4] = {bf, bi, bu, bo};
    const float* Ps[4] = {pf, pi, pu, po};

    // Deterministic wires 2,3: constants (accurate libm here, cheap & off hot path).
    float l2fc[2], Scc[2], occ[2], ricc[2];
#pragma unroll
    for (int w = 0; w < 2; ++w) {
        const int q = w + 2;
        float fv = 1.0f / (1.0f + expf(-cosf(Ps[0][q])));
        float iv = 1.0f / (1.0f + expf(-cosf(Ps[1][q])));
        float gv = tanhf(cosf(Ps[2][q]));
        float ov = 1.0f / (1.0f + expf(-cosf(Ps[3][q])));
        l2fc[w] = log2f(fv);            // fv in (0.26, 0.74): safe
        Scc[w] = iv * gv;
        occ[w] = ov;
        ricc[w] = 1.0f / (1.0f - fv);
    }
    // b_g[wire] + phi_g[wire] (wires 0,1) folded into hc.
    float bb[8];
#pragma unroll
    for (int g = 0; g < 4; ++g) {
#pragma unroll
        for (int wire = 0; wire < 2; ++wire) bb[g * 2 + wire] = Bs[g][wire] + Ps[g][wire];
    }

    // Stage deterministic sequences into LDS.
    for (int t = tid; t < TT; t += 64) {
        float h2, h3, ho2, ho3;
        {
            float ct = Scc[0] * (1.0f - exp2f((float)t * l2fc[0])) * ricc[0];
            h2 = occ[0] * tanhf(ct);
            float ct1 = Scc[0] * (1.0f - exp2f((float)(t + 1) * l2fc[0])) * ricc[0];
            ho2 = occ[0] * tanhf(ct1);
        }
        {
            float ct = Scc[1] * (1.0f - exp2f((float)t * l2fc[1])) * ricc[1];
            h3 = occ[1] * tanhf(ct);
            float ct1 = Scc[1] * (1.0f - exp2f((float)(t + 1) * l2fc[1])) * ricc[1];
            ho3 = occ[1] * tanhf(ct1);
        }
#pragma unroll
        for (int g = 0; g < 4; ++g) {
#pragma unroll
            for (int wire = 0; wire < 2; ++wire) {
                hc[t][g * 2 + wire] =
                    (bb[g * 2 + wire] + h2 * Ws[g][wire * 260 + 258] + h3 * Ws[g][wire * 260 + 259]) * INV2PI;
            }
        }
        hout[t][0] = ho2;
        hout[t][1] = ho3;
    }
    __syncthreads();

    // Recurrent weights for h0,h1 (pre-scaled to revolutions).
    float wr[8][2];
#pragma unroll
    for (int g = 0; g < 4; ++g) {
#pragma unroll
        for (int wire = 0; wire < 2; ++wire) {
#pragma unroll
            for (int j = 0; j < 2; ++j)
                wr[g * 2 + wire][j] = Ws[g][wire * 260 + 256 + j] * INV2PI;
        }
    }

    float h0 = 0.f, h1 = 0.f, c0 = 0.f, c1 = 0.f;
    const float* Zb = Z + (size_t)b * 8;
    float4 zbuf[8][2];  // 8-deep prefetch pipeline
#pragma unroll
    for (int t = 0; t < 8; ++t) {
        zbuf[t][0] = *(const float4*)(Zb + (size_t)t * 2048);
        zbuf[t][1] = *(const float4*)(Zb + (size_t)t * 2048 + 4);
    }
    float* outb = out + (size_t)b * 4;

#pragma unroll 8
    for (int t = 0; t < TT; ++t) {
        const int slot = t & 7;
        float4 zA = zbuf[slot][0], zB = zbuf[slot][1];
        if (t + 8 < TT) {
            zbuf[slot][0] = *(const float4*)(Zb + (size_t)(t + 8) * 2048);
            zbuf[slot][1] = *(const float4*)(Zb + (size_t)(t + 8) * 2048 + 4);
        }
        float4 hcA = *(const float4*)&hc[t][0];
        float4 hcB = *(const float4*)&hc[t][4];
        // angles in revolutions; h-independent part first so the fma chain off h is short
        float af0 = (zA.x + hcA.x) + h0 * wr[0][0] + h1 * wr[0][1];
        float af1 = (zA.y + hcA.y) + h0 * wr[1][0] + h1 * wr[1][1];
        float ai0 = (zA.z + hcA.z) + h0 * wr[2][0] + h1 * wr[2][1];
        float ai1 = (zA.w + hcA.w) + h0 * wr[3][0] + h1 * wr[3][1];
        float au0 = (zB.x + hcB.x) + h0 * wr[4][0] + h1 * wr[4][1];
        float au1 = (zB.y + hcB.y) + h0 * wr[5][0] + h1 * wr[5][1];
        float ao0 = (zB.z + hcB.z) + h0 * wr[6][0] + h1 * wr[6][1];
        float ao1 = (zB.w + hcB.w) + h0 * wr[7][0] + h1 * wr[7][1];
        float f0 = fast_sig(cosr(af0)), f1 = fast_sig(cosr(af1));
        float i0 = fast_sig(cosr(ai0)), i1 = fast_sig(cosr(ai1));
        float g0 = fast_tanh(cosr(au0)), g1 = fast_tanh(cosr(au1));
        float o0 = fast_sig(cosr(ao0)), o1 = fast_sig(cosr(ao1));
        c0 = f0 * c0 + i0 * g0;
        c1 = f1 * c1 + i1 * g1;
        h0 = o0 * fast_tanh(c0);
        h1 = o1 * fast_tanh(c1);
        float4 o4 = make_float4(h0, h1, hout[t][0], hout[t][1]);
        *(float4*)(outb + (size_t)t * (BB * 4)) = o4;
    }

    // hx = h_512 (== outputs[511]); cx = c_512.
    *(float4*)(out + (size_t)TT * BB * 4 + (size_t)b * 4) =
        make_float4(h0, h1, hout[TT - 1][0], hout[TT - 1][1]);
    float cd2 = Scc[0] * (1.0f - exp2f(512.0f * l2fc[0])) * ricc[0];
    float cd3 = Scc[1] * (1.0f - exp2f(512.0f * l2fc[1])) * ricc[1];
    *(float4*)(out + (size_t)TT * BB * 4 + (size_t)BB * 4 + (size_t)b * 4) =
        make_float4(c0, c1, cd2, cd3);
}

extern "C" void kernel_launch(void* const* d_in, const int* in_sizes, int n_in,
                              void* d_out, int out_size, void* d_ws, size_t ws_size,
                              hipStream_t stream) {
    (void)in_sizes; (void)n_in; (void)out_size; (void)ws_size;
    const float* x  = (const float*)d_in[0];
    const float* Wf = (const float*)d_in[1];
    const float* bf = (const float*)d_in[2];
    const float* pf = (const float*)d_in[3];
    const float* Wi = (const float*)d_in[4];
    const float* bi = (const float*)d_in[5];
    const float* pi = (const float*)d_in[6];
    const float* Wu = (const float*)d_in[7];
    const float* bu = (const float*)d_in[8];
    const float* pu = (const float*)d_in[9];
    const float* Wo = (const float*)d_in[10];
    const float* bo = (const float*)d_in[11];
    const float* po = (const float*)d_in[12];
    float* out = (float*)d_out;
    float* Z = (float*)d_ws;  // needs T*B*8*4 = 4 MiB of workspace

    qlstm_gemm<<<2048, 256, 0, stream>>>(x, Wf, Wi, Wu, Wo, Z);
    qlstm_scan<<<4, 64, 0, stream>>>(Z, Wf, bf, pf, Wi, bi, pi, Wu, bu, pu,
                                     Wo, bo, po, out);
}

// Round 3
// 308.298 us; speedup vs baseline: 1.1990x; 1.1990x over previous
//
#include <hip/hip_runtime.h>
#include <math.h>

// T=512, B=256, D=256, H=4. Gate wires 2,3 are input-independent -> closed form,
// computed per-block into LDS in the gemm and folded into Z / out cols 2,3.
// Scan carries only (h0,h1,c0,c1) per batch element; per-step stream is packed
// float2 (v_pk_fma_f32) with 8 v_cos + 4 v_rcp as the only trans ops.
#define TT 512
#define BB 256
#define DD 256
#define ROWS (TT * BB)          // 131072
#define INV2PI 0.15915494309189535f

typedef float v2f __attribute__((ext_vector_type(2)));
typedef float v4f __attribute__((ext_vector_type(4)));

__device__ __forceinline__ v2f pkfma(v2f a, v2f b, v2f c) {
    return __builtin_elementwise_fma(a, b, c);
}
__device__ __forceinline__ v2f cos2(v2f a) {
    v2f r;
    r.x = __builtin_amdgcn_cosf(a.x);   // v_cos_f32: cos(2*pi*x), HW range-reduced
    r.y = __builtin_amdgcn_cosf(a.y);
    return r;
}
// sigmoid(x), |x|<=1 (x is a cosine). Odd Taylor deg-7 about 0: max err ~2e-5.
__device__ __forceinline__ v2f sig2(v2f x) {
    v2f u = x * x;
    v2f p = pkfma(u, (v2f)(-2.1081349e-4f), (v2f)(2.0833333e-3f));
    p = pkfma(u, p, (v2f)(-2.0833333e-2f));
    p = pkfma(u, p, (v2f)(0.25f));
    return pkfma(x, p, (v2f)(0.5f));
}
// tanh(x), |x|<=~2.5: Pade CF4  x*(945+105u+u^2)/(945+420u+15u^2), err <2e-5.
__device__ __forceinline__ v2f tanh2(v2f x) {
    v2f u = x * x;
    v2f n = pkfma(u + (v2f)(105.0f), u, (v2f)(945.0f));
    v2f d = pkfma(pkfma(u, (v2f)(15.0f), (v2f)(420.0f)), u, (v2f)(945.0f));
    v2f r;
    r.x = __builtin_amdgcn_rcpf(d.x);
    r.y = __builtin_amdgcn_rcpf(d.y);
    return x * n * r;
}

// Multi-value butterfly: sum p[0..7] across 64 lanes, 10 shuffles.
// Lane l ends with the sum for value v = 4*(l&1) + 2*((l>>1)&1) + ((l>>2)&1).
__device__ __forceinline__ float reduce8(float p[8], int lane) {
    const bool b0 = lane & 1;
#pragma unroll
    for (int k = 0; k < 4; ++k) {
        float send = b0 ? p[k] : p[k + 4];
        float q = __shfl_xor(send, 1, 64);
        p[k] = (b0 ? p[k + 4] : p[k]) + q;
    }
    const bool b1 = lane & 2;
#pragma unroll
    for (int k = 0; k < 2; ++k) {
        float send = b1 ? p[k] : p[k + 2];
        float q = __shfl_xor(send, 2, 64);
        p[k] = (b1 ? p[k + 2] : p[k]) + q;
    }
    const bool b2 = lane & 4;
    {
        float send = b2 ? p[0] : p[1];
        float q = __shfl_xor(send, 4, 64);
        p[0] = (b2 ? p[1] : p[0]) + q;
    }
    p[0] += __shfl_xor(p[0], 8, 64);
    p[0] += __shfl_xor(p[0], 16, 64);
    p[0] += __shfl_xor(p[0], 32, 64);
    return p[0];
}

// Kernel A: Z[t,b,j] = (x[t,b,:].W_j)*INV2PI + hc[t][j]  (hc = b+phi+det-h terms,
// pre-scaled). Also writes out[t][b][2..3] = deterministic h columns.
__global__ __launch_bounds__(256) void qlstm_gemm(
    const float* __restrict__ x,
    const float* __restrict__ Wf, const float* __restrict__ bf, const float* __restrict__ pf,
    const float* __restrict__ Wi, const float* __restrict__ bi, const float* __restrict__ pi,
    const float* __restrict__ Wu, const float* __restrict__ bu, const float* __restrict__ pu,
    const float* __restrict__ Wo, const float* __restrict__ bo, const float* __restrict__ po,
    float* __restrict__ Z, float* __restrict__ out) {
    __shared__ float hcf[TT * 8];   // 16 KB: per-t constant part of angle (revolutions)
    __shared__ float hob[TT * 2];   // 4 KB:  h_{t+1}[2], h_{t+1}[3]
    const int tid = threadIdx.x;
    const float* Ws[4] = {Wf, Wi, Wu, Wo};
    const float* Bs[4] = {bf, bi, bu, bo};
    const float* Ps[4] = {pf, pi, pu, po};

    // ---- deterministic wires 2,3: closed form (every thread, cheap) ----
    float l2fc[2], Scc[2], occ[2], ricc[2];
#pragma unroll
    for (int w = 0; w < 2; ++w) {
        const int q = w + 2;
        float fv = 1.0f / (1.0f + expf(-cosf(Ps[0][q])));
        float iv = 1.0f / (1.0f + expf(-cosf(Ps[1][q])));
        float gv = tanhf(cosf(Ps[2][q]));
        float ov = 1.0f / (1.0f + expf(-cosf(Ps[3][q])));
        l2fc[w] = log2f(fv);
        Scc[w] = iv * gv;
        occ[w] = ov;
        ricc[w] = 1.0f / (1.0f - fv);
    }
    float bb[8];
#pragma unroll
    for (int g = 0; g < 4; ++g)
#pragma unroll
        for (int wire = 0; wire < 2; ++wire) bb[g * 2 + wire] = Bs[g][wire] + Ps[g][wire];

    for (int t = tid; t < TT; t += 256) {
        float h2 = occ[0] * tanhf(Scc[0] * (1.0f - exp2f((float)t * l2fc[0])) * ricc[0]);
        float h3 = occ[1] * tanhf(Scc[1] * (1.0f - exp2f((float)t * l2fc[1])) * ricc[1]);
        float ho2 = occ[0] * tanhf(Scc[0] * (1.0f - exp2f((float)(t + 1) * l2fc[0])) * ricc[0]);
        float ho3 = occ[1] * tanhf(Scc[1] * (1.0f - exp2f((float)(t + 1) * l2fc[1])) * ricc[1]);
#pragma unroll
        for (int g = 0; g < 4; ++g)
#pragma unroll
            for (int wire = 0; wire < 2; ++wire)
                hcf[t * 8 + g * 2 + wire] =
                    (bb[g * 2 + wire] + h2 * Ws[g][wire * 260 + 258] + h3 * Ws[g][wire * 260 + 259]) * INV2PI;
        hob[t * 2] = ho2;
        hob[t * 2 + 1] = ho3;
    }
    __syncthreads();

    // ---- main GEMM: one wave per row, 16 rows/wave, 4-row load pipeline ----
    const int lane = tid & 63;
    const int wid = (blockIdx.x * 256 + tid) >> 6;  // 0..8191
    float4 wv[8];
#pragma unroll
    for (int g = 0; g < 4; ++g)
#pragma unroll
        for (int wire = 0; wire < 2; ++wire)
            wv[g * 2 + wire] = *(const float4*)(Ws[g] + wire * 260 + 4 * lane);
    const int v = ((lane & 1) << 2) | (lane & 2) | ((lane >> 2) & 1);

#pragma unroll
    for (int k = 0; k < 16; k += 4) {
        v4f xv[4];
#pragma unroll
        for (int j = 0; j < 4; ++j) {
            const int r = wid + (k + j) * 8192;
            xv[j] = __builtin_nontemporal_load((const v4f*)(x + (size_t)r * DD + 4 * lane));
        }
        float s[4];
#pragma unroll
        for (int j = 0; j < 4; ++j) {
            float p[8];
#pragma unroll
            for (int m = 0; m < 8; ++m)
                p[m] = xv[j].x * wv[m].x + xv[j].y * wv[m].y + xv[j].z * wv[m].z + xv[j].w * wv[m].w;
            s[j] = reduce8(p, lane);
        }
        if (lane < 8) {
#pragma unroll
            for (int j = 0; j < 4; ++j) {
                const int r = wid + (k + j) * 8192;
                Z[(size_t)r * 8 + v] = s[j] * INV2PI + hcf[((r >> 8) << 3) + v];
            }
        } else if (lane < 12) {
            const int r = wid + (k + lane - 8) * 8192;
            *(float2*)(out + (size_t)r * 4 + 2) = *(const float2*)&hob[(r >> 8) * 2];
        }
    }
}

// Kernel B: 512-step scan, 4 waves total (one lane per batch element).
__global__ __launch_bounds__(64) void qlstm_scan(
    const float* __restrict__ Z,
    const float* __restrict__ Wf, const float* __restrict__ pf,
    const float* __restrict__ Wi, const float* __restrict__ pi,
    const float* __restrict__ Wu, const float* __restrict__ pu,
    const float* __restrict__ Wo, const float* __restrict__ po,
    float* __restrict__ out) {
    const int tid = threadIdx.x;
    const int b = blockIdx.x * 64 + tid;
    const float* Ws[4] = {Wf, Wi, Wu, Wo};
    const float* Ps[4] = {pf, pi, pu, po};

    // deterministic finals for the hx / cx rows
    float cd[2], hd[2];
#pragma unroll
    for (int w = 0; w < 2; ++w) {
        const int q = w + 2;
        float fv = 1.0f / (1.0f + expf(-cosf(Ps[0][q])));
        float iv = 1.0f / (1.0f + expf(-cosf(Ps[1][q])));
        float gv = tanhf(cosf(Ps[2][q]));
        float ov = 1.0f / (1.0f + expf(-cosf(Ps[3][q])));
        float l2f = log2f(fv);
        float S = iv * gv;
        float ric = 1.0f / (1.0f - fv);
        cd[w] = S * (1.0f - exp2f(512.0f * l2f)) * ric;
        hd[w] = ov * tanhf(cd[w]);
    }

    // recurrent weights (pre-scaled to revolutions), paired over wires
    v2f wa[4], wb[4];
#pragma unroll
    for (int g = 0; g < 4; ++g) {
        wa[g].x = Ws[g][256] * INV2PI;          // wire 0, h0
        wa[g].y = Ws[g][260 + 256] * INV2PI;    // wire 1, h0
        wb[g].x = Ws[g][257] * INV2PI;          // wire 0, h1
        wb[g].y = Ws[g][260 + 257] * INV2PI;    // wire 1, h1
    }

    v2f h = (v2f)(0.0f), c = (v2f)(0.0f);
    const float* Zb = Z + (size_t)b * 8;
    float* outp = out + (size_t)b * 4;
    v4f zbuf[8][2];  // 8-deep prefetch pipeline
#pragma unroll
    for (int t = 0; t < 8; ++t) {
        zbuf[t][0] = *(const v4f*)(Zb + (size_t)t * 2048);
        zbuf[t][1] = *(const v4f*)(Zb + (size_t)t * 2048 + 4);
    }

#pragma unroll 8
    for (int t = 0; t < TT; ++t) {
        const int slot = t & 7;
        v4f zA = zbuf[slot][0], zB = zbuf[slot][1];
        if (t + 8 < TT) {
            zbuf[slot][0] = *(const v4f*)(Zb + (size_t)(t + 8) * 2048);
            zbuf[slot][1] = *(const v4f*)(Zb + (size_t)(t + 8) * 2048 + 4);
        }
        v2f zf = {zA.x, zA.y}, zi = {zA.z, zA.w}, zu = {zB.x, zB.y}, zo = {zB.z, zB.w};
        v2f h0s = (v2f)(h.x), h1s = (v2f)(h.y);
        v2f af = pkfma(h0s, wa[0], pkfma(h1s, wb[0], zf));
        v2f ai = pkfma(h0s, wa[1], pkfma(h1s, wb[1], zi));
        v2f au = pkfma(h0s, wa[2], pkfma(h1s, wb[2], zu));
        v2f ao = pkfma(h0s, wa[3], pkfma(h1s, wb[3], zo));
        v2f f = sig2(cos2(af));
        v2f i = sig2(cos2(ai));
        v2f g = tanh2(cos2(au));
        v2f o = sig2(cos2(ao));
        c = pkfma(f, c, i * g);
        v2f th = tanh2(c);
        h = o * th;
        *(v2f*)(outp + (size_t)t * (BB * 4)) = h;  // cols 0,1 (cols 2,3 by gemm)
    }

    *(float4*)(out + (size_t)TT * BB * 4 + (size_t)b * 4) = make_float4(h.x, h.y, hd[0], hd[1]);
    *(float4*)(out + (size_t)TT * BB * 4 + (size_t)BB * 4 + (size_t)b * 4) =
        make_float4(c.x, c.y, cd[0], cd[1]);
}

extern "C" void kernel_launch(void* const* d_in, const int* in_sizes, int n_in,
                              void* d_out, int out_size, void* d_ws, size_t ws_size,
                              hipStream_t stream) {
    (void)in_sizes; (void)n_in; (void)out_size; (void)ws_size;
    const float* x  = (const float*)d_in[0];
    const float* Wf = (const float*)d_in[1];
    const float* bf = (const float*)d_in[2];
    const float* pf = (const float*)d_in[3];
    const float* Wi = (const float*)d_in[4];
    const float* bi = (const float*)d_in[5];
    const float* pi = (const float*)d_in[6];
    const float* Wu = (const float*)d_in[7];
    const float* bu = (const float*)d_in[8];
    const float* pu = (const float*)d_in[9];
    const float* Wo = (const float*)d_in[10];
    const float* bo = (const float*)d_in[11];
    const float* po = (const float*)d_in[12];
    float* out = (float*)d_out;
    float* Z = (float*)d_ws;  // T*B*8*4 = 4 MiB

    qlstm_gemm<<<2048, 256, 0, stream>>>(x, Wf, bf, pf, Wi, bi, pi, Wu, bu, pu,
                                         Wo, bo, po, Z, out);
    qlstm_scan<<<4, 64, 0, stream>>>(Z, Wf, pf, Wi, pi, Wu, pu, Wo, po, out);
}

// Round 5
// 233.633 us; speedup vs baseline: 1.5822x; 1.3196x over previous
//
#include <hip/hip_runtime.h>
#include <math.h>

// T=512, B=256, D=256, H=4. Wires 2,3 input-independent -> closed form (gemm).
// Scan: contractive recurrence (f<0.731) -> chunked-parallel with warm-up:
// 16 chunks x 32 steps, 40-step warm-up from h=c=0 (0.74^40 ~ 6e-6 error).
#define TT 512
#define BB 256
#define DD 256
#define ROWS (TT * BB)          // 131072
#define INV2PI 0.15915494309189535f
#define CHUNK 32
#define WARM 40
#define NCH (TT / CHUNK)        // 16

typedef float v2f __attribute__((ext_vector_type(2)));
typedef float v4f __attribute__((ext_vector_type(4)));

__device__ __forceinline__ v2f pkfma(v2f a, v2f b, v2f c) {
    return __builtin_elementwise_fma(a, b, c);
}
__device__ __forceinline__ v2f cos2(v2f a) {
    v2f r;
    r.x = __builtin_amdgcn_cosf(a.x);   // v_cos_f32: cos(2*pi*x), HW range-reduced
    r.y = __builtin_amdgcn_cosf(a.y);
    return r;
}
// sigmoid(x), |x|<=1. Odd Taylor deg-7: max err ~2e-5.
__device__ __forceinline__ v2f sig2(v2f x) {
    v2f u = x * x;
    v2f p = pkfma(u, (v2f)(-2.1081349e-4f), (v2f)(2.0833333e-3f));
    p = pkfma(u, p, (v2f)(-2.0833333e-2f));
    p = pkfma(u, p, (v2f)(0.25f));
    return pkfma(x, p, (v2f)(0.5f));
}
// tanh(x), |x|<=~2.5: Pade CF4  x*(945+105u+u^2)/(945+420u+15u^2), err <2e-5.
__device__ __forceinline__ v2f tanh2(v2f x) {
    v2f u = x * x;
    v2f n = pkfma(u + (v2f)(105.0f), u, (v2f)(945.0f));
    v2f d = pkfma(pkfma(u, (v2f)(15.0f), (v2f)(420.0f)), u, (v2f)(945.0f));
    v2f r;
    r.x = __builtin_amdgcn_rcpf(d.x);
    r.y = __builtin_amdgcn_rcpf(d.y);
    return x * n * r;
}

// Multi-value butterfly: sum p[0..7] across 64 lanes, 10 shuffles.
// Lane l ends with the sum for value v = 4*(l&1) + 2*((l>>1)&1) + ((l>>2)&1).
__device__ __forceinline__ float reduce8(float p[8], int lane) {
    const bool b0 = lane & 1;
#pragma unroll
    for (int k = 0; k < 4; ++k) {
        float send = b0 ? p[k] : p[k + 4];
        float q = __shfl_xor(send, 1, 64);
        p[k] = (b0 ? p[k + 4] : p[k]) + q;
    }
    const bool b1 = lane & 2;
#pragma unroll
    for (int k = 0; k < 2; ++k) {
        float send = b1 ? p[k] : p[k + 2];
        float q = __shfl_xor(send, 2, 64);
        p[k] = (b1 ? p[k + 2] : p[k]) + q;
    }
    const bool b2 = lane & 4;
    {
        float send = b2 ? p[0] : p[1];
        float q = __shfl_xor(send, 4, 64);
        p[0] = (b2 ? p[1] : p[0]) + q;
    }
    p[0] += __shfl_xor(p[0], 8, 64);
    p[0] += __shfl_xor(p[0], 16, 64);
    p[0] += __shfl_xor(p[0], 32, 64);
    return p[0];
}

// Kernel A: Z[t,b,j] = (x[t,b,:].W_j)*INV2PI + hc[t][j]; out[t][b][2..3] = det h.
__global__ __launch_bounds__(256) void qlstm_gemm(
    const float* __restrict__ x,
    const float* __restrict__ Wf, const float* __restrict__ bf, const float* __restrict__ pf,
    const float* __restrict__ Wi, const float* __restrict__ bi, const float* __restrict__ pi,
    const float* __restrict__ Wu, const float* __restrict__ bu, const float* __restrict__ pu,
    const float* __restrict__ Wo, const float* __restrict__ bo, const float* __restrict__ po,
    float* __restrict__ Z, float* __restrict__ out) {
    __shared__ float hcf[TT * 8];   // 16 KB: per-t constant part of angle (revolutions)
    __shared__ float hob[TT * 2];   // 4 KB:  h_{t+1}[2], h_{t+1}[3]
    const int tid = threadIdx.x;
    const float* Ws[4] = {Wf, Wi, Wu, Wo};
    const float* Bs[4] = {bf, bi, bu, bo};
    const float* Ps[4] = {pf, pi, pu, po};

    float l2fc[2], Scc[2], occ[2], ricc[2];
#pragma unroll
    for (int w = 0; w < 2; ++w) {
        const int q = w + 2;
        float fv = 1.0f / (1.0f + expf(-cosf(Ps[0][q])));
        float iv = 1.0f / (1.0f + expf(-cosf(Ps[1][q])));
        float gv = tanhf(cosf(Ps[2][q]));
        float ov = 1.0f / (1.0f + expf(-cosf(Ps[3][q])));
        l2fc[w] = log2f(fv);
        Scc[w] = iv * gv;
        occ[w] = ov;
        ricc[w] = 1.0f / (1.0f - fv);
    }
    float bb[8];
#pragma unroll
    for (int g = 0; g < 4; ++g)
#pragma unroll
        for (int wire = 0; wire < 2; ++wire) bb[g * 2 + wire] = Bs[g][wire] + Ps[g][wire];

    for (int t = tid; t < TT; t += 256) {
        float h2 = occ[0] * tanhf(Scc[0] * (1.0f - exp2f((float)t * l2fc[0])) * ricc[0]);
        float h3 = occ[1] * tanhf(Scc[1] * (1.0f - exp2f((float)t * l2fc[1])) * ricc[1]);
        float ho2 = occ[0] * tanhf(Scc[0] * (1.0f - exp2f((float)(t + 1) * l2fc[0])) * ricc[0]);
        float ho3 = occ[1] * tanhf(Scc[1] * (1.0f - exp2f((float)(t + 1) * l2fc[1])) * ricc[1]);
#pragma unroll
        for (int g = 0; g < 4; ++g)
#pragma unroll
            for (int wire = 0; wire < 2; ++wire)
                hcf[t * 8 + g * 2 + wire] =
                    (bb[g * 2 + wire] + h2 * Ws[g][wire * 260 + 258] + h3 * Ws[g][wire * 260 + 259]) * INV2PI;
        hob[t * 2] = ho2;
        hob[t * 2 + 1] = ho3;
    }
    __syncthreads();

    const int lane = tid & 63;
    const int wid = (blockIdx.x * 256 + tid) >> 6;  // 0..8191
    float4 wv[8];
#pragma unroll
    for (int g = 0; g < 4; ++g)
#pragma unroll
        for (int wire = 0; wire < 2; ++wire)
            wv[g * 2 + wire] = *(const float4*)(Ws[g] + wire * 260 + 4 * lane);
    const int v = ((lane & 1) << 2) | (lane & 2) | ((lane >> 2) & 1);

#pragma unroll
    for (int k = 0; k < 16; k += 4) {
        v4f xv[4];
#pragma unroll
        for (int j = 0; j < 4; ++j) {
            const int r = wid + (k + j) * 8192;
            xv[j] = *(const v4f*)(x + (size_t)r * DD + 4 * lane);  // cached: x fits L3
        }
        float s[4];
#pragma unroll
        for (int j = 0; j < 4; ++j) {
            float p[8];
#pragma unroll
            for (int m = 0; m < 8; ++m)
                p[m] = xv[j].x * wv[m].x + xv[j].y * wv[m].y + xv[j].z * wv[m].z + xv[j].w * wv[m].w;
            s[j] = reduce8(p, lane);
        }
        if (lane < 8) {
#pragma unroll
            for (int j = 0; j < 4; ++j) {
                const int r = wid + (k + j) * 8192;
                Z[(size_t)r * 8 + v] = s[j] * INV2PI + hcf[((r >> 8) << 3) + v];
            }
        } else if (lane < 12) {
            const int r = wid + (k + lane - 8) * 8192;
            *(float2*)(out + (size_t)r * 4 + 2) = *(const float2*)&hob[(r >> 8) * 2];
        }
    }
}

// Kernel B: chunked-parallel scan. Grid = NCH*4 blocks x 64 threads.
// block -> (chunk, bgroup); lane = batch elem in group. Warm-up from h=c=0 at
// tw = max(0, t0-WARM) (recurrence contracts at f<=0.731/step), emit CHUNK steps.
__global__ __launch_bounds__(64) void qlstm_scan(
    const float* __restrict__ Z,
    const float* __restrict__ Wf, const float* __restrict__ pf,
    const float* __restrict__ Wi, const float* __restrict__ pi,
    const float* __restrict__ Wu, const float* __restrict__ pu,
    const float* __restrict__ Wo, const float* __restrict__ po,
    float* __restrict__ out) {
    const int tid = threadIdx.x;
    const int chunk = blockIdx.x >> 2;
    const int b = (blockIdx.x & 3) * 64 + tid;
    const float* Ws[4] = {Wf, Wi, Wu, Wo};
    const float* Ps[4] = {pf, pi, pu, po};

    // deterministic finals for the hx / cx rows (only chunk NCH-1 uses them)
    float cd[2], hd[2];
#pragma unroll
    for (int w = 0; w < 2; ++w) {
        const int q = w + 2;
        float fv = 1.0f / (1.0f + expf(-cosf(Ps[0][q])));
        float iv = 1.0f / (1.0f + expf(-cosf(Ps[1][q])));
        float gv = tanhf(cosf(Ps[2][q]));
        float ov = 1.0f / (1.0f + expf(-cosf(Ps[3][q])));
        float l2f = log2f(fv);
        float S = iv * gv;
        float ric = 1.0f / (1.0f - fv);
        cd[w] = S * (1.0f - exp2f(512.0f * l2f)) * ric;
        hd[w] = ov * tanhf(cd[w]);
    }

    v2f wa[4], wb[4];
#pragma unroll
    for (int g = 0; g < 4; ++g) {
        wa[g].x = Ws[g][256] * INV2PI;          // wire 0, h0
        wa[g].y = Ws[g][260 + 256] * INV2PI;    // wire 1, h0
        wb[g].x = Ws[g][257] * INV2PI;          // wire 0, h1
        wb[g].y = Ws[g][260 + 257] * INV2PI;    // wire 1, h1
    }

    const int t0 = chunk * CHUNK;
    const int tw = (t0 - WARM > 0) ? (t0 - WARM) : 0;  // clamp: chunk 0 -> 0, chunk 1 -> 0
    const int len = t0 + CHUNK - tw;                   // 32, 64, or 72

    v2f h = (v2f)(0.0f), c = (v2f)(0.0f);
    const float* Zb = Z + (size_t)b * 8;  // row t at +t*2048 floats
    float* outp = out + (size_t)b * 4;
    v4f zbuf[8][2];
#pragma unroll
    for (int s = 0; s < 8; ++s) {
        zbuf[s][0] = *(const v4f*)(Zb + (size_t)(tw + s) * 2048);
        zbuf[s][1] = *(const v4f*)(Zb + (size_t)(tw + s) * 2048 + 4);
    }

#pragma unroll 8
    for (int s = 0; s < len; ++s) {
        const int t = tw + s;
        const int slot = s & 7;
        v4f zA = zbuf[slot][0], zB = zbuf[slot][1];
        if (s + 8 < len) {
            zbuf[slot][0] = *(const v4f*)(Zb + (size_t)(t + 8) * 2048);
            zbuf[slot][1] = *(const v4f*)(Zb + (size_t)(t + 8) * 2048 + 4);
        }
        v2f zf = {zA.x, zA.y}, zi = {zA.z, zA.w}, zu = {zB.x, zB.y}, zo = {zB.z, zB.w};
        v2f h0s = (v2f)(h.x), h1s = (v2f)(h.y);
        v2f af = pkfma(h0s, wa[0], pkfma(h1s, wb[0], zf));
        v2f ai = pkfma(h0s, wa[1], pkfma(h1s, wb[1], zi));
        v2f au = pkfma(h0s, wa[2], pkfma(h1s, wb[2], zu));
        v2f ao = pkfma(h0s, wa[3], pkfma(h1s, wb[3], zo));
        v2f f = sig2(cos2(af));
        v2f i = sig2(cos2(ai));
        v2f g = tanh2(cos2(au));
        v2f o = sig2(cos2(ao));
        c = pkfma(f, c, i * g);
        v2f th = tanh2(c);
        h = o * th;
        if (t >= t0)
            *(v2f*)(outp + (size_t)t * (BB * 4)) = h;  // cols 0,1 (2,3 by gemm)
    }

    if (chunk == NCH - 1) {
        *(float4*)(out + (size_t)TT * BB * 4 + (size_t)b * 4) =
            make_float4(h.x, h.y, hd[0], hd[1]);
        *(float4*)(out + (size_t)TT * BB * 4 + (size_t)BB * 4 + (size_t)b * 4) =
            make_float4(c.x, c.y, cd[0], cd[1]);
    }
}

extern "C" void kernel_launch(void* const* d_in, const int* in_sizes, int n_in,
                              void* d_out, int out_size, void* d_ws, size_t ws_size,
                              hipStream_t stream) {
    (void)in_sizes; (void)n_in; (void)out_size; (void)ws_size;
    const float* x  = (const float*)d_in[0];
    const float* Wf = (const float*)d_in[1];
    const float* bf = (const float*)d_in[2];
    const float* pf = (const float*)d_in[3];
    const float* Wi = (const float*)d_in[4];
    const float* bi = (const float*)d_in[5];
    const float* pi = (const float*)d_in[6];
    const float* Wu = (const float*)d_in[7];
    const float* bu = (const float*)d_in[8];
    const float* pu = (const float*)d_in[9];
    const float* Wo = (const float*)d_in[10];
    const float* bo = (const float*)d_in[11];
    const float* po = (const float*)d_in[12];
    float* out = (float*)d_out;
    float* Z = (float*)d_ws;  // T*B*8*4 = 4 MiB

    qlstm_gemm<<<2048, 256, 0, stream>>>(x, Wf, bf, pf, Wi, bi, pi, Wu, bu, pu,
                                         Wo, bo, po, Z, out);
    qlstm_scan<<<NCH * 4, 64, 0, stream>>>(Z, Wf, pf, Wi, pi, Wu, pu, Wo, po, out);
}